// Round 3
// baseline (185.202 us; speedup 1.0000x reference)
//
#include <hip/hip_runtime.h>
#include <hip/hip_cooperative_groups.h>
#include <math.h>

namespace cg = cooperative_groups;

constexpr int NB = 8;    // batch
constexpr int NF = 32;   // features
constexpr int NN = 512;  // nodes
constexpr int NH = 8;    // hidden
constexpr int KCH = 32;  // column-sum chunks
constexpr int KROWS = NN / KCH;
constexpr int GRID = 1024;  // 4 blocks/CU on 256 CUs -> co-resident

// ---------------------------------------------------------------------------
// Fused cooperative kernel: colsum partials -> grid.sync -> u/v -> grid.sync
// -> output sweep (grid-strided).
// ---------------------------------------------------------------------------
__global__ __launch_bounds__(256, 4) void fused_kernel(
    const float* __restrict__ adj, const float* __restrict__ emb,
    const float* __restrict__ W1, const float* __restrict__ b1,
    const float* __restrict__ W2, const float* __restrict__ b2,
    float* __restrict__ out, float* __restrict__ ws)
{
    cg::grid_group grid = cg::this_grid();
    float* part = ws;                        // KCH*NN floats
    float* u    = ws + KCH * NN;             // NB*NN*NH floats
    float* v    = u + NB * NN * NH;          // NB*NN*NH floats

    const int gid = blockIdx.x * 256 + threadIdx.x;

    // ---- phase 1: partial column sums of adj[0] (coalesced in n) ----
    if (gid < KCH * NN) {
        const int c = gid >> 9;              // gid / NN
        const int n = gid & (NN - 1);
        const float* p = adj + (size_t)(c * KROWS) * NN + n;
        float acc = 0.f;
        #pragma unroll
        for (int k = 0; k < KROWS; ++k)
            acc += p[(size_t)k * NN];
        part[gid] = acc;
    }
    grid.sync();

    // ---- phase 2: u[b,n,:], v[b,n,:] ----
    if (gid < NB * NN) {
        const int b = gid >> 9;
        const int n = gid & (NN - 1);

        float cs = 0.f;
        #pragma unroll
        for (int c = 0; c < KCH; ++c)
            cs += part[c * NN + n];

        const float dg = adj[((size_t)b * NN + n) * NN + n];
        const float sw = (cs - dg) * (1.0f / (float)(NN - 1));

        float uo[NH], vo[NH];
        #pragma unroll
        for (int k = 0; k < NH; ++k) {
            uo[k] = 0.f;
            vo[k] = b1[k] + sw * W1[2 * NF * NH + k];
        }
        for (int f = 0; f < NF; ++f) {
            const float e = emb[((size_t)b * NF + f) * NN + n];
            #pragma unroll
            for (int k = 0; k < NH; ++k) {
                uo[k] = fmaf(e, W1[f * NH + k],        uo[k]);
                vo[k] = fmaf(e, W1[(NF + f) * NH + k], vo[k]);
            }
        }
        float4* u4 = reinterpret_cast<float4*>(u);
        float4* v4 = reinterpret_cast<float4*>(v);
        u4[gid * 2 + 0] = make_float4(uo[0], uo[1], uo[2], uo[3]);
        u4[gid * 2 + 1] = make_float4(uo[4], uo[5], uo[6], uo[7]);
        v4[gid * 2 + 0] = make_float4(vo[0], vo[1], vo[2], vo[3]);
        v4[gid * 2 + 1] = make_float4(vo[4], vo[5], vo[6], vo[7]);
    }
    grid.sync();

    // ---- phase 3: out[b,i,j] = sigmoid(b2 + sum_k relu(u_ik+v_jk)*W2_k) ----
    float w2[NH];
    #pragma unroll
    for (int k = 0; k < NH; ++k) w2[k] = W2[k];
    const float bias = b2[0];
    const float4* v4 = reinterpret_cast<const float4*>(v);

    for (int row = blockIdx.x; row < NB * NN; row += GRID) {
        const int b  = row >> 9;
        const int j0 = threadIdx.x * 2;

        float ur[NH];
        #pragma unroll
        for (int k = 0; k < NH; ++k) ur[k] = u[row * NH + k];

        const int vi = (b * NN + j0) * 2;
        const float4 va0 = v4[vi + 0];
        const float4 vb0 = v4[vi + 1];
        const float4 va1 = v4[vi + 2];
        const float4 vb1 = v4[vi + 3];
        const float vv0[NH] = {va0.x, va0.y, va0.z, va0.w, vb0.x, vb0.y, vb0.z, vb0.w};
        const float vv1[NH] = {va1.x, va1.y, va1.z, va1.w, vb1.x, vb1.y, vb1.z, vb1.w};

        float a0 = bias, a1 = bias;
        #pragma unroll
        for (int k = 0; k < NH; ++k) {
            a0 = fmaf(fmaxf(ur[k] + vv0[k], 0.f), w2[k], a0);
            a1 = fmaf(fmaxf(ur[k] + vv1[k], 0.f), w2[k], a1);
        }
        float2 o;
        o.x = 1.0f / (1.0f + __expf(-a0));
        o.y = 1.0f / (1.0f + __expf(-a1));
        reinterpret_cast<float2*>(out + (size_t)row * NN)[threadIdx.x] = o;
    }
}

// ---------------------------------------------------------------------------
// Fallback path (proven round-2 kernels) if cooperative launch is rejected.
// ---------------------------------------------------------------------------
__global__ __launch_bounds__(256) void colsum_part_kernel(
    const float* __restrict__ adj, float* __restrict__ part)
{
    const int n = blockIdx.x * 256 + threadIdx.x;
    const int c = blockIdx.y;
    const float* p = adj + (size_t)c * KROWS * NN + n;
    float acc = 0.f;
    #pragma unroll
    for (int k = 0; k < KROWS; ++k)
        acc += p[(size_t)k * NN];
    part[c * NN + n] = acc;
}

__global__ __launch_bounds__(256) void uv_kernel(
    const float* __restrict__ adj, const float* __restrict__ emb,
    const float* __restrict__ W1, const float* __restrict__ b1,
    const float* __restrict__ part,
    float* __restrict__ u, float* __restrict__ v)
{
    const int idx = blockIdx.x * 256 + threadIdx.x;
    const int b = idx >> 9;
    const int n = idx & (NN - 1);

    float cs = 0.f;
    #pragma unroll
    for (int c = 0; c < KCH; ++c)
        cs += part[c * NN + n];

    const float dg = adj[((size_t)b * NN + n) * NN + n];
    const float sw = (cs - dg) * (1.0f / (float)(NN - 1));

    float uo[NH], vo[NH];
    #pragma unroll
    for (int k = 0; k < NH; ++k) {
        uo[k] = 0.f;
        vo[k] = b1[k] + sw * W1[2 * NF * NH + k];
    }
    for (int f = 0; f < NF; ++f) {
        const float e = emb[((size_t)b * NF + f) * NN + n];
        #pragma unroll
        for (int k = 0; k < NH; ++k) {
            uo[k] = fmaf(e, W1[f * NH + k],        uo[k]);
            vo[k] = fmaf(e, W1[(NF + f) * NH + k], vo[k]);
        }
    }
    float4* u4 = reinterpret_cast<float4*>(u);
    float4* v4 = reinterpret_cast<float4*>(v);
    u4[idx * 2 + 0] = make_float4(uo[0], uo[1], uo[2], uo[3]);
    u4[idx * 2 + 1] = make_float4(uo[4], uo[5], uo[6], uo[7]);
    v4[idx * 2 + 0] = make_float4(vo[0], vo[1], vo[2], vo[3]);
    v4[idx * 2 + 1] = make_float4(vo[4], vo[5], vo[6], vo[7]);
}

__global__ __launch_bounds__(256) void out_kernel(
    const float* __restrict__ u, const float* __restrict__ v,
    const float* __restrict__ W2, const float* __restrict__ b2,
    float* __restrict__ out)
{
    const int row = blockIdx.x;
    const int b   = row >> 9;
    const int j0  = threadIdx.x * 2;

    float ur[NH];
    #pragma unroll
    for (int k = 0; k < NH; ++k) ur[k] = u[row * NH + k];
    float w2[NH];
    #pragma unroll
    for (int k = 0; k < NH; ++k) w2[k] = W2[k];
    const float bias = b2[0];

    const float4* v4 = reinterpret_cast<const float4*>(v);
    const int vi = (b * NN + j0) * 2;
    const float4 va0 = v4[vi + 0];
    const float4 vb0 = v4[vi + 1];
    const float4 va1 = v4[vi + 2];
    const float4 vb1 = v4[vi + 3];
    const float vv0[NH] = {va0.x, va0.y, va0.z, va0.w, vb0.x, vb0.y, vb0.z, vb0.w};
    const float vv1[NH] = {va1.x, va1.y, va1.z, va1.w, vb1.x, vb1.y, vb1.z, vb1.w};

    float a0 = bias, a1 = bias;
    #pragma unroll
    for (int k = 0; k < NH; ++k) {
        a0 = fmaf(fmaxf(ur[k] + vv0[k], 0.f), w2[k], a0);
        a1 = fmaf(fmaxf(ur[k] + vv1[k], 0.f), w2[k], a1);
    }
    float2 o;
    o.x = 1.0f / (1.0f + __expf(-a0));
    o.y = 1.0f / (1.0f + __expf(-a1));
    reinterpret_cast<float2*>(out + (size_t)row * NN)[threadIdx.x] = o;
}

extern "C" void kernel_launch(void* const* d_in, const int* in_sizes, int n_in,
                              void* d_out, int out_size, void* d_ws, size_t ws_size,
                              hipStream_t stream) {
    const float* adj = (const float*)d_in[0];
    const float* emb = (const float*)d_in[1];
    const float* W1  = (const float*)d_in[2];
    const float* b1  = (const float*)d_in[3];
    const float* W2  = (const float*)d_in[4];
    const float* b2  = (const float*)d_in[5];
    float* out = (float*)d_out;
    float* ws  = (float*)d_ws;   // part(16K) + u(32K) + v(32K) floats = 320 KB

    void* args[] = {(void*)&adj, (void*)&emb, (void*)&W1, (void*)&b1,
                    (void*)&W2,  (void*)&b2,  (void*)&out, (void*)&ws};
    hipError_t err = hipLaunchCooperativeKernel(
        reinterpret_cast<const void*>(fused_kernel),
        dim3(GRID), dim3(256), args, 0, stream);

    if (err != hipSuccess) {
        // Fallback: proven 3-kernel pipeline.
        float* u    = ws + KCH * NN;
        float* v    = u + NB * NN * NH;
        float* part = ws;
        colsum_part_kernel<<<dim3(NN / 256, KCH), 256, 0, stream>>>(adj, part);
        uv_kernel<<<dim3(NB * NN / 256), 256, 0, stream>>>(adj, emb, W1, b1, part, u, v);
        out_kernel<<<dim3(NB * NN), 256, 0, stream>>>(u, v, W2, b2, out);
    }
}

// Round 4
// 15.337 us; speedup vs baseline: 12.0753x; 12.0753x over previous
//
#include <hip/hip_runtime.h>
#include <math.h>

constexpr int NB = 8;    // batch
constexpr int NF = 32;   // features
constexpr int NN = 512;  // nodes
constexpr int NH = 8;    // hidden
constexpr int NCHUNK = 64;   // columns per K1 block
constexpr int IPB = 4;       // output rows per K2 block

// ---------------------------------------------------------------------------
// Kernel 1 (fused colsum + u/v): one block per (batch b, 64-column chunk).
// Phase A: block-local column sums of adj[0] for its 64 columns (4 row-chunks
//          across the 4 waves, LDS-reduced).  8x redundant across b -> L2.
// Phase B: partial u/v over 8 features per wave, LDS-reduced.
// Phase C: first wave finalizes sw, u, v and stores.
//   u[b,n,k] = sum_f emb[b,f,n] * W1[f,k]
//   v[b,n,k] = sum_f emb[b,f,n] * W1[F+f,k] + sw[b,n]*W1[2F,k] + b1[k]
//   sw[b,n]  = (colsum0[n] - adj[b,n,n]) / (N-1)
// ---------------------------------------------------------------------------
__global__ __launch_bounds__(256) void uv_fused_kernel(
    const float* __restrict__ adj, const float* __restrict__ emb,
    const float* __restrict__ W1, const float* __restrict__ b1,
    float* __restrict__ u, float* __restrict__ v)
{
    __shared__ float lds_cs[4][NCHUNK];        // 1 KB
    __shared__ float lds_u[4][NH][NCHUNK];     // 8 KB
    __shared__ float lds_v[4][NH][NCHUNK];     // 8 KB

    const int nc = blockIdx.x;          // column chunk [0,8)
    const int b  = blockIdx.y;          // batch [0,8)
    const int n0 = nc * NCHUNK;
    const int lo = threadIdx.x & 63;    // column within chunk / lane
    const int hi = threadIdx.x >> 6;    // wave id [0,4)

    // ---- phase A: colsum partial (rows hi*128 .. hi*128+127), coalesced ----
    {
        const float* p = adj + (size_t)(hi * 128) * NN + n0 + lo;
        float acc = 0.f;
        #pragma unroll 8
        for (int k = 0; k < 128; ++k)
            acc += p[(size_t)k * NN];
        lds_cs[hi][lo] = acc;
    }

    // ---- phase B: u/v partial over features hi*8 .. hi*8+7 ----
    {
        float uo[NH], vo[NH];
        #pragma unroll
        for (int k = 0; k < NH; ++k) { uo[k] = 0.f; vo[k] = 0.f; }
        #pragma unroll
        for (int f8 = 0; f8 < 8; ++f8) {
            const int f = hi * 8 + f8;
            const float e = emb[((size_t)b * NF + f) * NN + n0 + lo]; // coalesced
            #pragma unroll
            for (int k = 0; k < NH; ++k) {
                uo[k] = fmaf(e, W1[f * NH + k],        uo[k]);  // wave-uniform
                vo[k] = fmaf(e, W1[(NF + f) * NH + k], vo[k]);
            }
        }
        #pragma unroll
        for (int k = 0; k < NH; ++k) {
            lds_u[hi][k][lo] = uo[k];   // bank = lane%32 -> 2-way, free
            lds_v[hi][k][lo] = vo[k];
        }
    }
    __syncthreads();

    // ---- phase C: wave 0 finalizes 64 (b,n) pairs ----
    if (threadIdx.x < 64) {
        const int n = n0 + lo;
        const float cs = lds_cs[0][lo] + lds_cs[1][lo] + lds_cs[2][lo] + lds_cs[3][lo];
        const float dg = adj[((size_t)b * NN + n) * NN + n];
        const float sw = (cs - dg) * (1.0f / (float)(NN - 1));

        float uo[NH], vo[NH];
        #pragma unroll
        for (int k = 0; k < NH; ++k) {
            uo[k] = lds_u[0][k][lo] + lds_u[1][k][lo] + lds_u[2][k][lo] + lds_u[3][k][lo];
            vo[k] = lds_v[0][k][lo] + lds_v[1][k][lo] + lds_v[2][k][lo] + lds_v[3][k][lo]
                  + b1[k] + sw * W1[2 * NF * NH + k];
        }
        const int idx = b * NN + n;
        float4* u4 = reinterpret_cast<float4*>(u);
        float4* v4 = reinterpret_cast<float4*>(v);
        u4[idx * 2 + 0] = make_float4(uo[0], uo[1], uo[2], uo[3]);
        u4[idx * 2 + 1] = make_float4(uo[4], uo[5], uo[6], uo[7]);
        v4[idx * 2 + 0] = make_float4(vo[0], vo[1], vo[2], vo[3]);
        v4[idx * 2 + 1] = make_float4(vo[4], vo[5], vo[6], vo[7]);
    }
}

// ---------------------------------------------------------------------------
// Kernel 2: out[b,i,j] = sigmoid(b2 + sum_k relu(u[b,i,k]+v[b,j,k]) * W2[k])
// One block per (b, 4-row group); each thread produces 2 j's x 4 rows.
// v fragments loaded once per thread and reused across the 4 rows.
// ---------------------------------------------------------------------------
__global__ __launch_bounds__(256) void out_kernel(
    const float* __restrict__ u, const float* __restrict__ v,
    const float* __restrict__ W2, const float* __restrict__ b2,
    float* __restrict__ out)
{
    const int b  = blockIdx.y;
    const int i0 = blockIdx.x * IPB;
    const int j0 = threadIdx.x * 2;

    float w2[NH];
    #pragma unroll
    for (int k = 0; k < NH; ++k) w2[k] = W2[k];
    const float bias = b2[0];

    const float4* v4 = reinterpret_cast<const float4*>(v);
    const int vi = (b * NN + j0) * 2;
    const float4 va0 = v4[vi + 0];
    const float4 vb0 = v4[vi + 1];
    const float4 va1 = v4[vi + 2];
    const float4 vb1 = v4[vi + 3];
    const float vv0[NH] = {va0.x, va0.y, va0.z, va0.w, vb0.x, vb0.y, vb0.z, vb0.w};
    const float vv1[NH] = {va1.x, va1.y, va1.z, va1.w, vb1.x, vb1.y, vb1.z, vb1.w};

    #pragma unroll
    for (int r = 0; r < IPB; ++r) {
        const int row = b * NN + i0 + r;

        float ur[NH];
        #pragma unroll
        for (int k = 0; k < NH; ++k) ur[k] = u[row * NH + k];  // wave-uniform

        float a0 = bias, a1 = bias;
        #pragma unroll
        for (int k = 0; k < NH; ++k) {
            a0 = fmaf(fmaxf(ur[k] + vv0[k], 0.f), w2[k], a0);
            a1 = fmaf(fmaxf(ur[k] + vv1[k], 0.f), w2[k], a1);
        }
        float2 o;
        o.x = 1.0f / (1.0f + __expf(-a0));
        o.y = 1.0f / (1.0f + __expf(-a1));
        reinterpret_cast<float2*>(out + (size_t)row * NN)[threadIdx.x] = o;
    }
}

extern "C" void kernel_launch(void* const* d_in, const int* in_sizes, int n_in,
                              void* d_out, int out_size, void* d_ws, size_t ws_size,
                              hipStream_t stream) {
    const float* adj = (const float*)d_in[0];
    const float* emb = (const float*)d_in[1];
    const float* W1  = (const float*)d_in[2];
    const float* b1  = (const float*)d_in[3];
    const float* W2  = (const float*)d_in[4];
    const float* b2  = (const float*)d_in[5];
    float* out = (float*)d_out;

    float* u = (float*)d_ws;               // NB*NN*NH floats
    float* v = u + NB * NN * NH;           // NB*NN*NH floats

    uv_fused_kernel<<<dim3(NN / NCHUNK, NB), 256, 0, stream>>>(adj, emb, W1, b1, u, v);
    out_kernel<<<dim3(NN / IPB, NB), 256, 0, stream>>>(u, v, W2, b2, out);
}

// Round 5
// 11.838 us; speedup vs baseline: 15.6442x; 1.2956x over previous
//
#include <hip/hip_runtime.h>
#include <math.h>

constexpr int NB = 8;    // batch
constexpr int NF = 32;   // features
constexpr int NN = 512;  // nodes
constexpr int NH = 8;    // hidden
constexpr int JC = 32;   // columns per block
constexpr int IR = 256;  // rows per block (half the node range)

// ---------------------------------------------------------------------------
// Single fused kernel. Block = (jc, ih, b) owns out[b, ih*256 .. +255,
// jc*32 .. +31]. It self-computes:
//   waves 4-7: colsum partials of adj[0] for its 32 columns -> cs_lds
//   waves 0-3: u[k][i] for its 256 rows -> u_lds   (u = emb . W1[:F])
//   32 thr:    v[k][j] for its 32 cols  -> v_lds   (v = emb . W1[F:2F]
//                                                   + sw*W1[2F] + b1)
//   all:       out[b,i,j] = sigmoid(b2 + sum_k relu(u+v)*W2)
// Redundancy: colsum x2 (i-halves), u x16 (col chunks) -- all L2-resident.
// ---------------------------------------------------------------------------
__global__ __launch_bounds__(512) void fused1_kernel(
    const float* __restrict__ adj, const float* __restrict__ emb,
    const float* __restrict__ W1, const float* __restrict__ b1,
    const float* __restrict__ W2, const float* __restrict__ b2,
    float* __restrict__ out)
{
    __shared__ float u_lds[NH][IR];   // 8 KB
    __shared__ float v_lds[NH][JC];   // 1 KB
    __shared__ float cs_lds[8][JC];   // 1 KB

    const int jc = blockIdx.x;        // [0,16)
    const int ih = blockIdx.y;        // [0,2)
    const int b  = blockIdx.z;        // [0,8)
    const int j0 = jc * JC;
    const int i0 = ih * IR;
    const int t  = threadIdx.x;       // [0,512)

    if (t < 256) {
        // ---- u for rows i0 .. i0+255 (coalesced emb reads) ----
        const int i = i0 + t;
        float uo[NH];
        #pragma unroll
        for (int k = 0; k < NH; ++k) uo[k] = 0.f;
        #pragma unroll 8
        for (int f = 0; f < NF; ++f) {
            const float e = emb[((size_t)b * NF + f) * NN + i];
            #pragma unroll
            for (int k = 0; k < NH; ++k)
                uo[k] = fmaf(e, W1[f * NH + k], uo[k]);   // W1 wave-uniform
        }
        #pragma unroll
        for (int k = 0; k < NH; ++k) u_lds[k][t] = uo[k]; // bank=t%32, clean
    } else {
        // ---- colsum partials: 32 cols x 8 row-groups of 64 rows ----
        const int tt = t - 256;
        const int c  = tt & 31;
        const int rg = tt >> 5;                           // [0,8)
        const float* p = adj + (size_t)(rg * 64) * NN + j0 + c;
        float acc = 0.f;
        #pragma unroll 16
        for (int r = 0; r < 64; ++r)
            acc += p[(size_t)r * NN];                     // 128B/row-group segs
        cs_lds[rg][c] = acc;
    }
    __syncthreads();

    if (t >= 256 && t < 256 + JC) {
        // ---- finalize sw + v for the 32 columns ----
        const int c = t - 256;
        const int n = j0 + c;
        float cs = 0.f;
        #pragma unroll
        for (int rg = 0; rg < 8; ++rg) cs += cs_lds[rg][c];
        const float dg = adj[((size_t)b * NN + n) * NN + n];
        const float sw = (cs - dg) * (1.0f / (float)(NN - 1));

        float vo[NH];
        #pragma unroll
        for (int k = 0; k < NH; ++k)
            vo[k] = b1[k] + sw * W1[2 * NF * NH + k];
        #pragma unroll 8
        for (int f = 0; f < NF; ++f) {
            const float e = emb[((size_t)b * NF + f) * NN + n];
            #pragma unroll
            for (int k = 0; k < NH; ++k)
                vo[k] = fmaf(e, W1[(NF + f) * NH + k], vo[k]);
        }
        #pragma unroll
        for (int k = 0; k < NH; ++k) v_lds[k][c] = vo[k];
    }
    __syncthreads();

    // ---- output sweep: thread owns column j, 16 rows ----
    float w2[NH];
    #pragma unroll
    for (int k = 0; k < NH; ++k) w2[k] = W2[k];
    const float bias = b2[0];

    const int j    = t & 31;
    const int isub = t >> 5;                              // [0,16)

    float vv[NH];
    #pragma unroll
    for (int k = 0; k < NH; ++k) vv[k] = v_lds[k][j];     // bank-clean

    float* orow = out + ((size_t)b * NN + i0) * NN + j0 + j;
    #pragma unroll 4
    for (int r = 0; r < 16; ++r) {
        const int i = isub * 16 + r;
        float a = bias;
        #pragma unroll
        for (int k = 0; k < NH; ++k)
            a = fmaf(fmaxf(u_lds[k][i] + vv[k], 0.f), w2[k], a);  // 2-addr bcast
        orow[(size_t)i * NN] = 1.0f / (1.0f + __expf(-a));  // 2x128B segs/wave
    }
}

extern "C" void kernel_launch(void* const* d_in, const int* in_sizes, int n_in,
                              void* d_out, int out_size, void* d_ws, size_t ws_size,
                              hipStream_t stream) {
    const float* adj = (const float*)d_in[0];
    const float* emb = (const float*)d_in[1];
    const float* W1  = (const float*)d_in[2];
    const float* b1  = (const float*)d_in[3];
    const float* W2  = (const float*)d_in[4];
    const float* b2  = (const float*)d_in[5];
    float* out = (float*)d_out;

    fused1_kernel<<<dim3(NN / JC, NN / IR, NB), 512, 0, stream>>>(
        adj, emb, W1, b1, W2, b2, out);
}